// Round 5
// baseline (276.555 us; speedup 1.0000x reference)
//
#include <hip/hip_runtime.h>
#include <hip/hip_bf16.h>

typedef __bf16 bf16_t;
typedef __bf16 v8bf __attribute__((ext_vector_type(8)));
typedef float  v4f  __attribute__((ext_vector_type(4)));

#define MFMA16(a, b, c) __builtin_amdgcn_mfma_f32_16x16x32_bf16((a), (b), (c), 0, 0, 0)

#define GLDS16(g, l) __builtin_amdgcn_global_load_lds(                         \
    (const __attribute__((address_space(1))) void*)(g),                        \
    (__attribute__((address_space(3))) void*)(l), 16, 0, 0)

#define B_SZ   2
#define SEQ    2048
#define DM     1024
#define NH     16
#define HD     64
#define M_TOT  4096

// 0.125 * log2(e): Q pre-scale so softmax exps need no multiply
#define QSCALE 0.18033688011112043f

// ---------------------------------------------------------------------------
// convert x fp32 -> bf16  (4M elems, 8/thread)
// ---------------------------------------------------------------------------
__global__ __launch_bounds__(256)
void conv_x_kernel(const float* __restrict__ src, bf16_t* __restrict__ dst)
{
    int i = (blockIdx.x * 256 + threadIdx.x) * 8;
    float4 a = *reinterpret_cast<const float4*>(src + i);
    float4 b = *reinterpret_cast<const float4*>(src + i + 4);
    union { bf16_t h[8]; int4 v; } u;
    u.h[0] = (bf16_t)a.x; u.h[1] = (bf16_t)a.y; u.h[2] = (bf16_t)a.z; u.h[3] = (bf16_t)a.w;
    u.h[4] = (bf16_t)b.x; u.h[5] = (bf16_t)b.y; u.h[6] = (bf16_t)b.z; u.h[7] = (bf16_t)b.w;
    *reinterpret_cast<int4*>(dst + i) = u.v;
}

// ---------------------------------------------------------------------------
// transpose+convert W fp32 [k][n] -> bf16 [n][k].  grid (32,32,4)
// ---------------------------------------------------------------------------
__global__ __launch_bounds__(256)
void conv_wt_kernel(const float* __restrict__ Wq, const float* __restrict__ Wk,
                    const float* __restrict__ Wv, const float* __restrict__ Wo,
                    bf16_t* __restrict__ WqkvT, bf16_t* __restrict__ WoT)
{
    __shared__ float t[32][33];
    const int z = blockIdx.z;
    const float* src = (z == 0) ? Wq : (z == 1) ? Wk : (z == 2) ? Wv : Wo;
    bf16_t* dst = (z < 3) ? (WqkvT + (size_t)z * 1048576) : WoT;
    const int tx = threadIdx.x & 31, ty = threadIdx.x >> 5;
    const int c0 = blockIdx.x * 32, r0 = blockIdx.y * 32;
#pragma unroll
    for (int i = 0; i < 4; ++i)
        t[ty + i * 8][tx] = src[(size_t)(r0 + ty + i * 8) * DM + c0 + tx];
    __syncthreads();
#pragma unroll
    for (int i = 0; i < 4; ++i)
        dst[(size_t)(c0 + ty + i * 8) * DM + r0 + tx] = (bf16_t)t[tx][ty + i * 8];
}

// ---------------------------------------------------------------------------
// GEMM via global_load_lds (m97 structure): C[M][N] = A[M][K] @ BT[N][K]^T.
// Unpadded 128x64 LDS tiles; 16B chunks XOR-swizzled c' = c ^ (r&7) so the
// frag ds_read_b128 stays <=2-way while the DMA dest is lane-contiguous.
// MODE 1: fused QKV (mat=bx>>3): mat0->Qb [B,H,S,hd] scaled QSCALE,
//         mat1->Kb [B,H,S,hd], mat2->Vb [B,H,hd,S].
// MODE 0: final projection, fp32 out row-major.
// ---------------------------------------------------------------------------
template <int MODE>
__global__ __launch_bounds__(256)
void gemm_bt_kernel(const bf16_t* __restrict__ A, const bf16_t* __restrict__ BT,
                    const float* __restrict__ b0, const float* __restrict__ b1,
                    const float* __restrict__ b2,
                    void* __restrict__ oQ, void* __restrict__ oK, void* __restrict__ oV)
{
    __shared__ __align__(16) bf16_t As[128 * 64];
    __shared__ __align__(16) bf16_t Bs[128 * 64];

    const int tid  = threadIdx.x;
    const int lane = tid & 63;
    const int wave = tid >> 6;
    const int wm   = (wave >> 1) * 64;
    const int wn   = (wave & 1) * 64;
    const int quad = lane >> 4;
    const int l15  = lane & 15;
    const int l7   = l15 & 7;

    int mat, n0;
    const bf16_t* Bmat;
    if (MODE == 1) { mat = blockIdx.x >> 3; n0 = (blockIdx.x & 7) * 128;
                     Bmat = BT + (size_t)mat * 1048576; }
    else           { mat = 0; n0 = blockIdx.x * 128; Bmat = BT; }
    const int m0 = blockIdx.y * 128;

    const v4f vzero = {0.f, 0.f, 0.f, 0.f};
    v4f acc[4][4];
#pragma unroll
    for (int mt = 0; mt < 4; ++mt)
#pragma unroll
        for (int nt = 0; nt < 4; ++nt) acc[mt][nt] = vzero;

    for (int it = 0; it < 16; ++it) {
        const int k0 = it * 64;
        // stage both tiles: 1024 chunks each, 4 DMA insts per wave per tile
#pragma unroll
        for (int i = 0; i < 4; ++i) {
            int cidx = (wave * 4 + i) * 64 + lane;   // chunk 0..1023
            int r = cidx >> 3;
            int c = (cidx & 7) ^ (r & 7);            // global chunk for this slot
            GLDS16(A    + (size_t)(m0 + r) * DM + k0 + c * 8, As + (wave * 4 + i) * 512);
            GLDS16(Bmat + (size_t)(n0 + r) * DM + k0 + c * 8, Bs + (wave * 4 + i) * 512);
        }
        __syncthreads();
#pragma unroll
        for (int ks = 0; ks < 2; ++ks) {
            v8bf af[4], bfq[4];
#pragma unroll
            for (int mt = 0; mt < 4; ++mt)
                af[mt] = *reinterpret_cast<const v8bf*>(
                    &As[(wm + mt * 16 + l15) * 64 + ((ks * 4 + quad) ^ l7) * 8]);
#pragma unroll
            for (int nt = 0; nt < 4; ++nt)
                bfq[nt] = *reinterpret_cast<const v8bf*>(
                    &Bs[(wn + nt * 16 + l15) * 64 + ((ks * 4 + quad) ^ l7) * 8]);
#pragma unroll
            for (int mt = 0; mt < 4; ++mt)
#pragma unroll
                for (int nt = 0; nt < 4; ++nt)
                    acc[mt][nt] = MFMA16(af[mt], bfq[nt], acc[mt][nt]);
        }
        __syncthreads();
    }

    const float* bias = (MODE == 1) ? (mat == 0 ? b0 : mat == 1 ? b1 : b2) : b0;
    const float scale = (MODE == 1 && mat == 0) ? QSCALE : 1.0f;
#pragma unroll
    for (int mt = 0; mt < 4; ++mt) {
#pragma unroll
        for (int nt = 0; nt < 4; ++nt) {
            int col = n0 + wn + nt * 16 + l15;
            float bv = bias[col];
#pragma unroll
            for (int r = 0; r < 4; ++r) {
                int row = m0 + wm + mt * 16 + quad * 4 + r;
                float v = (acc[mt][nt][r] + bv) * scale;
                if (MODE == 0) {
                    reinterpret_cast<float*>(oQ)[(size_t)row * DM + col] = v;
                } else {
                    int b = row >> 11, s = row & 2047;
                    int h = col >> 6,  d = col & 63;
                    if (mat == 2)
                        reinterpret_cast<bf16_t*>(oV)[((size_t)(b * NH + h) * HD + d) * SEQ + s] = (bf16_t)v;
                    else {
                        bf16_t* dst = (mat == 0) ? (bf16_t*)oQ : (bf16_t*)oK;
                        dst[((size_t)(b * NH + h) * SEQ + s) * HD + d] = (bf16_t)v;
                    }
                }
            }
        }
    }
}

// ---------------------------------------------------------------------------
// Flash attention, causal, S^T formulation, wave-balanced split strips.
// Block j handles q-strips [64j,64j+64) and [64(31-j),..+64); wave w owns
// 16 rows of EACH strip -> every wave computes exactly 33 subtile-iters.
// S^T = K Q^T: lane holds one q (=l15), 16 keys in-lane; softmax in-lane +
// 2 shuffles; P^T packed ds_write_b64; O^T = V^T P^T.
// Q pre-scaled by 0.125*log2(e).  Q,K [B,H,S,hd]; V [B,H,hd,S]; O [B,S,D].
// ---------------------------------------------------------------------------
__global__ __launch_bounds__(256)
void attn_kernel(const bf16_t* __restrict__ Q, const bf16_t* __restrict__ K,
                 const bf16_t* __restrict__ Vt, bf16_t* __restrict__ O)
{
    __shared__ __align__(16) bf16_t QPs[128 * 72];
    __shared__ __align__(16) bf16_t Ks[2][64 * 72];
    __shared__ __align__(16) bf16_t Vs[2][64 * 72];

    const int tid  = threadIdx.x;
    const int lane = tid & 63;
    const int w    = tid >> 6;
    const int quad = lane >> 4;
    const int l15  = lane & 15;
    const int j    = blockIdx.x;          // 0..15
    const int bh   = blockIdx.y;
    const int sA   = 64 * j;              // strip a: short causal extent
    const int sB   = 64 * (31 - j);       // strip b: long causal extent
    const size_t base = (size_t)bh * SEQ * HD;

    const bf16_t* Qg = Q  + base;
    const bf16_t* Kg = K  + base;
    const bf16_t* Vg = Vt + base;

    // load Q: QPs rows 0..63 = strip a, 64..127 = strip b
#pragma unroll
    for (int i = 0; i < 4; ++i) {
        int c = tid + i * 256;
        int row = c >> 3, oct = c & 7;
        int grow = (row < 64) ? (sA + row) : (sB + row - 64);
        *reinterpret_cast<int4*>(&QPs[row * 72 + oct * 8]) =
            *reinterpret_cast<const int4*>(Qg + (size_t)grow * HD + oct * 8);
    }
    __syncthreads();

    // q fragments (B-operand: n=q=l15, k=d); qtile0 row w*16, qtile1 row 64+w*16
    v8bf qf[2][2];
#pragma unroll
    for (int qtile = 0; qtile < 2; ++qtile)
#pragma unroll
        for (int ks = 0; ks < 2; ++ks)
            qf[qtile][ks] = *reinterpret_cast<const v8bf*>(
                &QPs[(qtile * 64 + w * 16 + l15) * 72 + ks * 32 + quad * 8]);

    const v4f vzero = {0.f, 0.f, 0.f, 0.f};
    v4f acc_o[4][2];                 // [dtile][qtile]  O^T: row=d, col=q
    float mrow[2], lrow[2];
#pragma unroll
    for (int dt = 0; dt < 4; ++dt)
#pragma unroll
        for (int qtile = 0; qtile < 2; ++qtile) acc_o[dt][qtile] = vzero;
    mrow[0] = mrow[1] = -1e30f;
    lrow[0] = lrow[1] = 0.f;

    const int nkt    = 32 - j;           // key tiles needed (strip b limit)
    const int limit1 = 31 - j;           // diag iter for strip b

    // prefetch tile 0
    int4 kreg[2], vreg[2];
#pragma unroll
    for (int i = 0; i < 2; ++i) {
        int c = tid + i * 256;
        int row = c >> 3, oct = c & 7;
        kreg[i] = *reinterpret_cast<const int4*>(Kg + (size_t)row * HD + oct * 8);
        vreg[i] = *reinterpret_cast<const int4*>(Vg + (size_t)row * SEQ + oct * 8);
    }

    for (int kt = 0; kt < nkt; ++kt) {
        const int cur = kt & 1;
#pragma unroll
        for (int i = 0; i < 2; ++i) {
            int c = tid + i * 256;
            int row = c >> 3, oct = c & 7;
            *reinterpret_cast<int4*>(&Ks[cur][row * 72 + oct * 8]) = kreg[i];
            *reinterpret_cast<int4*>(&Vs[cur][row * 72 + oct * 8]) = vreg[i];
        }
        if (kt + 1 < nkt) {
            const int nt0 = (kt + 1) * 64;
#pragma unroll
            for (int i = 0; i < 2; ++i) {
                int c = tid + i * 256;
                int row = c >> 3, oct = c & 7;
                kreg[i] = *reinterpret_cast<const int4*>(Kg + (size_t)(nt0 + row) * HD + oct * 8);
                vreg[i] = *reinterpret_cast<const int4*>(Vg + (size_t)row * SEQ + nt0 + oct * 8);
            }
        }
        __syncthreads();

        const bool act0 = (kt <= j);     // strip a still active? (block-uniform)

        // S^T = K Q^T
        v4f st[4][2];
#pragma unroll
        for (int ktile = 0; ktile < 4; ++ktile)
#pragma unroll
            for (int qtile = 0; qtile < 2; ++qtile) st[ktile][qtile] = vzero;
#pragma unroll
        for (int ks = 0; ks < 2; ++ks) {
            v8bf kb[4];
#pragma unroll
            for (int ktile = 0; ktile < 4; ++ktile)
                kb[ktile] = *reinterpret_cast<const v8bf*>(
                    &Ks[cur][(ktile * 16 + l15) * 72 + ks * 32 + quad * 8]);
#pragma unroll
            for (int ktile = 0; ktile < 4; ++ktile) {
                st[ktile][1] = MFMA16(kb[ktile], qf[1][ks], st[ktile][1]);
                if (act0)
                    st[ktile][0] = MFMA16(kb[ktile], qf[0][ks], st[ktile][0]);
            }
        }

#pragma unroll
        for (int qtile = 0; qtile < 2; ++qtile) {
            if (qtile == 0 && !act0) continue;
            const int  sbase = (qtile == 0) ? sA : sB;
            const bool diagI = (qtile == 0) ? (kt == j) : (kt == limit1);
            const int  qg    = sbase + w * 16 + l15;
            float rm = -1e30f;
#pragma unroll
            for (int ktile = 0; ktile < 4; ++ktile) {
                if (diagI && ktile > w) continue;       // fully masked subtile
#pragma unroll
                for (int r = 0; r < 4; ++r) {
                    float v = st[ktile][qtile][r];
                    if (diagI && ktile == w) {
                        int kg = kt * 64 + ktile * 16 + quad * 4 + r;
                        if (kg > qg) v = -1e30f;
                    }
                    st[ktile][qtile][r] = v;
                    rm = fmaxf(rm, v);
                }
            }
            rm = fmaxf(rm, __shfl_xor(rm, 16));
            rm = fmaxf(rm, __shfl_xor(rm, 32));
            float mn = fmaxf(mrow[qtile], rm);
            float alpha = exp2f(mrow[qtile] - mn);
            mrow[qtile] = mn;
            float rs = 0.f;
            const int prow = (qtile * 64 + w * 16 + l15) * 72;
#pragma unroll
            for (int ktile = 0; ktile < 4; ++ktile) {
                union { bf16_t h[4]; int2 v; } u;
                if (diagI && ktile > w) {
                    u.v.x = 0; u.v.y = 0;
                } else {
#pragma unroll
                    for (int r = 0; r < 4; ++r) {
                        float p = exp2f(st[ktile][qtile][r] - mn);
                        rs += p;
                        u.h[r] = (bf16_t)p;
                    }
                }
                *reinterpret_cast<int2*>(&QPs[prow + ktile * 16 + quad * 4]) = u.v;
            }
            rs += __shfl_xor(rs, 16);
            rs += __shfl_xor(rs, 32);
            lrow[qtile] = lrow[qtile] * alpha + rs;
#pragma unroll
            for (int dt = 0; dt < 4; ++dt)
#pragma unroll
                for (int r = 0; r < 4; ++r)
                    acc_o[dt][qtile][r] *= alpha;
        }

        // O^T += V^T P^T  (same-wave LDS round-trip, no barrier needed)
#pragma unroll
        for (int ks = 0; ks < 2; ++ks) {
            v8bf vb[4], pf0, pf1;
#pragma unroll
            for (int dt = 0; dt < 4; ++dt)
                vb[dt] = *reinterpret_cast<const v8bf*>(
                    &Vs[cur][(dt * 16 + l15) * 72 + ks * 32 + quad * 8]);
            pf1 = *reinterpret_cast<const v8bf*>(
                &QPs[(64 + w * 16 + l15) * 72 + ks * 32 + quad * 8]);
            if (act0)
                pf0 = *reinterpret_cast<const v8bf*>(
                    &QPs[(w * 16 + l15) * 72 + ks * 32 + quad * 8]);
#pragma unroll
            for (int dt = 0; dt < 4; ++dt) {
                acc_o[dt][1] = MFMA16(vb[dt], pf1, acc_o[dt][1]);
                if (act0)
                    acc_o[dt][0] = MFMA16(vb[dt], pf0, acc_o[dt][0]);
            }
        }
    }

    // epilogue: lane holds q=l15 (col), d=quad*4+r per dtile -> d-contig int2
    const int bO = bh >> 4, hO = bh & 15;
#pragma unroll
    for (int qtile = 0; qtile < 2; ++qtile) {
        float rinv = 1.f / lrow[qtile];
        int s = ((qtile == 0) ? sA : sB) + w * 16 + l15;
#pragma unroll
        for (int dt = 0; dt < 4; ++dt) {
            union { bf16_t h[4]; int2 v; } u;
#pragma unroll
            for (int r = 0; r < 4; ++r)
                u.h[r] = (bf16_t)(acc_o[dt][qtile][r] * rinv);
            *reinterpret_cast<int2*>(
                &O[((size_t)bO * SEQ + s) * DM + hO * 64 + dt * 16 + quad * 4]) = u.v;
        }
    }
}

// ---------------------------------------------------------------------------
extern "C" void kernel_launch(void* const* d_in, const int* in_sizes, int n_in,
                              void* d_out, int out_size, void* d_ws, size_t ws_size,
                              hipStream_t stream) {
    const float* x  = (const float*)d_in[0];
    const float* Wq = (const float*)d_in[1];
    const float* bq = (const float*)d_in[2];
    const float* Wk = (const float*)d_in[3];
    const float* bk = (const float*)d_in[4];
    const float* Wv = (const float*)d_in[5];
    const float* bv = (const float*)d_in[6];
    const float* Wo = (const float*)d_in[7];
    const float* bo = (const float*)d_in[8];

    bf16_t* ws = (bf16_t*)d_ws;
    bf16_t* xb     = ws;                   // [4096,1024]        4M   (dead after QKV)
    bf16_t* WqkvT  = ws + 4194304;         // [3,1024n,1024k]    3M
    bf16_t* WoT    = ws + 7340032;         // [1024n,1024k]      1M
    bf16_t* Qb     = ws + 8388608;         // [B,H,S,hd]  pre-scaled 0.125*log2(e)
    bf16_t* Kb     = ws + 12582912;        // [B,H,S,hd]
    bf16_t* Vb     = ws + 16777216;        // [B,H,hd,S]
    bf16_t* Ob     = ws;                   // [B,S,D]  aliases xb (stream-ordered safe)

    conv_x_kernel<<<2048, 256, 0, stream>>>(x, xb);
    conv_wt_kernel<<<dim3(32, 32, 4), 256, 0, stream>>>(Wq, Wk, Wv, Wo, WqkvT, WoT);
    gemm_bt_kernel<1><<<dim3(24, 32), 256, 0, stream>>>(xb, WqkvT, bq, bk, bv, Qb, Kb, Vb);
    attn_kernel<<<dim3(16, 32), 256, 0, stream>>>(Qb, Kb, Vb, Ob);
    gemm_bt_kernel<0><<<dim3(8, 32), 256, 0, stream>>>(Ob, WoT, bo, nullptr, nullptr,
                                                       d_out, nullptr, nullptr);
}

// Round 6
// 214.956 us; speedup vs baseline: 1.2866x; 1.2866x over previous
//
#include <hip/hip_runtime.h>
#include <hip/hip_bf16.h>

typedef __bf16 bf16_t;
typedef __bf16 v8bf __attribute__((ext_vector_type(8)));
typedef float  v4f  __attribute__((ext_vector_type(4)));

#define MFMA16(a, b, c) __builtin_amdgcn_mfma_f32_16x16x32_bf16((a), (b), (c), 0, 0, 0)

#define GLDS16(g, l) __builtin_amdgcn_global_load_lds(                         \
    (const __attribute__((address_space(1))) void*)(g),                        \
    (__attribute__((address_space(3))) void*)(l), 16, 0, 0)

#define B_SZ   2
#define SEQ    2048
#define DM     1024
#define NH     16
#define HD     64
#define M_TOT  4096

// 0.125 * log2(e): Q pre-scale so softmax exps need no multiply
#define QSCALE 0.18033688011112043f

// ---------------------------------------------------------------------------
// convert x fp32 -> bf16  (4M elems, 8/thread)
// ---------------------------------------------------------------------------
__global__ __launch_bounds__(256)
void conv_x_kernel(const float* __restrict__ src, bf16_t* __restrict__ dst)
{
    int i = (blockIdx.x * 256 + threadIdx.x) * 8;
    float4 a = *reinterpret_cast<const float4*>(src + i);
    float4 b = *reinterpret_cast<const float4*>(src + i + 4);
    union { bf16_t h[8]; int4 v; } u;
    u.h[0] = (bf16_t)a.x; u.h[1] = (bf16_t)a.y; u.h[2] = (bf16_t)a.z; u.h[3] = (bf16_t)a.w;
    u.h[4] = (bf16_t)b.x; u.h[5] = (bf16_t)b.y; u.h[6] = (bf16_t)b.z; u.h[7] = (bf16_t)b.w;
    *reinterpret_cast<int4*>(dst + i) = u.v;
}

// ---------------------------------------------------------------------------
// transpose+convert W fp32 [k][n] -> bf16 [n][k].  grid (32,32,4)
// ---------------------------------------------------------------------------
__global__ __launch_bounds__(256)
void conv_wt_kernel(const float* __restrict__ Wq, const float* __restrict__ Wk,
                    const float* __restrict__ Wv, const float* __restrict__ Wo,
                    bf16_t* __restrict__ WqkvT, bf16_t* __restrict__ WoT)
{
    __shared__ float t[32][33];
    const int z = blockIdx.z;
    const float* src = (z == 0) ? Wq : (z == 1) ? Wk : (z == 2) ? Wv : Wo;
    bf16_t* dst = (z < 3) ? (WqkvT + (size_t)z * 1048576) : WoT;
    const int tx = threadIdx.x & 31, ty = threadIdx.x >> 5;
    const int c0 = blockIdx.x * 32, r0 = blockIdx.y * 32;
#pragma unroll
    for (int i = 0; i < 4; ++i)
        t[ty + i * 8][tx] = src[(size_t)(r0 + ty + i * 8) * DM + c0 + tx];
    __syncthreads();
#pragma unroll
    for (int i = 0; i < 4; ++i)
        dst[(size_t)(c0 + ty + i * 8) * DM + r0 + tx] = (bf16_t)t[tx][ty + i * 8];
}

// ---------------------------------------------------------------------------
// GEMM via global_load_lds: C[M][N] = A[M][K] @ BT[N][K]^T + bias.
// Unpadded 128x64 LDS tiles, 16B chunks XOR-swizzled (c' = c ^ (r&7)).
// MODE 1 fused QKV (mat=bx>>3): mat0->Qb [B,H,S,hd] scaled QSCALE,
//   mat1->Kb [B,H,S,hd], mat2->Vb [B,H,hd,S] via TRANSPOSED accumulation
//   (operand-swapped MFMA) so the s-dim store is contiguous.
// MODE 0: final projection, fp32 out row-major.
// ---------------------------------------------------------------------------
template <int MODE>
__global__ __launch_bounds__(256)
void gemm_bt_kernel(const bf16_t* __restrict__ A, const bf16_t* __restrict__ BT,
                    const float* __restrict__ b0, const float* __restrict__ b1,
                    const float* __restrict__ b2,
                    void* __restrict__ oQ, void* __restrict__ oK, void* __restrict__ oV)
{
    __shared__ __align__(16) bf16_t As[128 * 64];
    __shared__ __align__(16) bf16_t Bs[128 * 64];

    const int tid  = threadIdx.x;
    const int lane = tid & 63;
    const int wave = tid >> 6;
    const int wm   = (wave >> 1) * 64;
    const int wn   = (wave & 1) * 64;
    const int quad = lane >> 4;
    const int l15  = lane & 15;
    const int l7   = l15 & 7;

    int mat, n0;
    const bf16_t* Bmat;
    if (MODE == 1) { mat = blockIdx.x >> 3; n0 = (blockIdx.x & 7) * 128;
                     Bmat = BT + (size_t)mat * 1048576; }
    else           { mat = 0; n0 = blockIdx.x * 128; Bmat = BT; }
    const int m0 = blockIdx.y * 128;
    const bool transC = (MODE == 1) && (mat == 2);

    const v4f vzero = {0.f, 0.f, 0.f, 0.f};
    v4f acc[4][4];
#pragma unroll
    for (int mt = 0; mt < 4; ++mt)
#pragma unroll
        for (int nt = 0; nt < 4; ++nt) acc[mt][nt] = vzero;

    for (int it = 0; it < 16; ++it) {
        const int k0 = it * 64;
#pragma unroll
        for (int i = 0; i < 4; ++i) {
            int cidx = (wave * 4 + i) * 64 + lane;   // chunk 0..1023
            int r = cidx >> 3;
            int c = (cidx & 7) ^ (r & 7);
            GLDS16(A    + (size_t)(m0 + r) * DM + k0 + c * 8, As + (wave * 4 + i) * 512);
            GLDS16(Bmat + (size_t)(n0 + r) * DM + k0 + c * 8, Bs + (wave * 4 + i) * 512);
        }
        __syncthreads();
#pragma unroll
        for (int ks = 0; ks < 2; ++ks) {
            v8bf af[4], bfq[4];
#pragma unroll
            for (int mt = 0; mt < 4; ++mt)
                af[mt] = *reinterpret_cast<const v8bf*>(
                    &As[(wm + mt * 16 + l15) * 64 + ((ks * 4 + quad) ^ l7) * 8]);
#pragma unroll
            for (int nt = 0; nt < 4; ++nt)
                bfq[nt] = *reinterpret_cast<const v8bf*>(
                    &Bs[(wn + nt * 16 + l15) * 64 + ((ks * 4 + quad) ^ l7) * 8]);
            if (!transC) {
#pragma unroll
                for (int mt = 0; mt < 4; ++mt)
#pragma unroll
                    for (int nt = 0; nt < 4; ++nt)
                        acc[mt][nt] = MFMA16(af[mt], bfq[nt], acc[mt][nt]);
            } else {
#pragma unroll
                for (int mt = 0; mt < 4; ++mt)
#pragma unroll
                    for (int nt = 0; nt < 4; ++nt)
                        acc[mt][nt] = MFMA16(bfq[nt], af[mt], acc[mt][nt]);
            }
        }
        __syncthreads();
    }

    const float* bias = (MODE == 1) ? (mat == 0 ? b0 : mat == 1 ? b1 : b2) : b0;
    if (!transC) {
        const float scale = (MODE == 1 && mat == 0) ? QSCALE : 1.0f;
#pragma unroll
        for (int mt = 0; mt < 4; ++mt) {
#pragma unroll
            for (int nt = 0; nt < 4; ++nt) {
                int col = n0 + wn + nt * 16 + l15;
                float bv = bias[col];
#pragma unroll
                for (int r = 0; r < 4; ++r) {
                    int row = m0 + wm + mt * 16 + quad * 4 + r;
                    float v = (acc[mt][nt][r] + bv) * scale;
                    if (MODE == 0) {
                        reinterpret_cast<float*>(oQ)[(size_t)row * DM + col] = v;
                    } else {
                        int b = row >> 11, s = row & 2047;
                        int h = col >> 6,  d = col & 63;
                        bf16_t* dst = (mat == 0) ? (bf16_t*)oQ : (bf16_t*)oK;
                        dst[((size_t)(b * NH + h) * SEQ + s) * HD + d] = (bf16_t)v;
                    }
                }
            }
        }
    } else {
        // acc[mt][nt] holds C^T: lane l15 = s-row (m-side), reg r = n-col
#pragma unroll
        for (int nt = 0; nt < 4; ++nt) {
#pragma unroll
            for (int r = 0; r < 4; ++r) {
                int coln = n0 + wn + nt * 16 + quad * 4 + r;   // h*64+d
                float bv = bias[coln];
                int h = coln >> 6, d = coln & 63;
#pragma unroll
                for (int mt = 0; mt < 4; ++mt) {
                    int srow = m0 + wm + mt * 16 + l15;
                    int b = srow >> 11, s = srow & 2047;
                    reinterpret_cast<bf16_t*>(oV)[
                        ((size_t)(b * NH + h) * HD + d) * SEQ + s] =
                        (bf16_t)(acc[mt][nt][r] + bv);
                }
            }
        }
    }
}

// ---------------------------------------------------------------------------
// Flash attention, causal.  Block = 64 q-rows (tile t); wave w owns rows
// [64t+16w, +16).  Balanced CU mapping: u=(x+(y&24))&31 -> t in
// {s,31-s,8+s,23-s} per CU (66 iters/CU constant).  K/V staged by
// global_load_lds into unpadded XOR-swizzled 8KB tiles; Q frags direct
// global->reg; P in small per-wave-private LDS.  LDS=25.6KB -> 6 blocks/CU.
// Q pre-scaled 0.125*log2(e).  Q,K [B,H,S,hd]; V [B,H,hd,S]; O [B,S,D].
// ---------------------------------------------------------------------------
__global__ __launch_bounds__(256)
void attn_kernel(const bf16_t* __restrict__ Q, const bf16_t* __restrict__ K,
                 const bf16_t* __restrict__ Vt, bf16_t* __restrict__ O)
{
    __shared__ __align__(16) bf16_t Ks[64 * 64];
    __shared__ __align__(16) bf16_t Vs[64 * 64];
    __shared__ __align__(16) bf16_t Ps[64 * 72];

    const int tid  = threadIdx.x;
    const int lane = tid & 63;
    const int w    = tid >> 6;
    const int quad = lane >> 4;
    const int l15  = lane & 15;
    const int l7   = lane & 7;

    const int x = blockIdx.x, y = blockIdx.y;
    const int u_ = (x + (y & 24)) & 31;
    const int r_ = u_ >> 3, s_ = u_ & 7;
    const int t  = (r_ == 0) ? s_ : (r_ == 1) ? 31 - s_ : (r_ == 2) ? 8 + s_ : 23 - s_;
    const int bh = y;
    const int q0 = t * 64;
    const size_t base = (size_t)bh * SEQ * HD;

    const bf16_t* Qg = Q  + base;
    const bf16_t* Kg = K  + base;
    const bf16_t* Vg = Vt + base;

    // Q fragments direct from global (B-operand: n=q=l15, k=d=quad*8+j)
    v8bf qf[2];
    {
        const bf16_t* qrow = Qg + (size_t)(q0 + w * 16 + l15) * HD;
        qf[0] = *reinterpret_cast<const v8bf*>(qrow + quad * 8);
        qf[1] = *reinterpret_cast<const v8bf*>(qrow + 32 + quad * 8);
    }

    const v4f vzero = {0.f, 0.f, 0.f, 0.f};
    v4f acc_o[4];
#pragma unroll
    for (int dt = 0; dt < 4; ++dt) acc_o[dt] = vzero;
    float mrow = -1e30f, lrow = 0.f;
    const int qg = q0 + w * 16 + l15;       // this lane's q row

    for (int kt = 0; kt <= t; ++kt) {
        // stage K tile (keys x d) and V^T tile (d x keys), 8KB each, swizzled
        {
            const bf16_t* Kt0 = Kg + (size_t)kt * 64 * HD;
            const bf16_t* Vt0 = Vg + kt * 64;
#pragma unroll
            for (int i = 0; i < 2; ++i) {
                int cidx = i * 256 + tid;            // 0..511
                int rr = cidx >> 3;
                int cc = (cidx & 7) ^ (rr & 7);
                GLDS16(Kt0 + (size_t)rr * HD  + cc * 8, Ks + (i * 256 + w * 64) * 8);
                GLDS16(Vt0 + (size_t)rr * SEQ + cc * 8, Vs + (i * 256 + w * 64) * 8);
            }
        }
        __syncthreads();

        // S^T = K Q^T  (A=K: m=key=l15, k=d; B=Q)
        v4f st[4];
#pragma unroll
        for (int ktile = 0; ktile < 4; ++ktile) st[ktile] = vzero;
#pragma unroll
        for (int ks = 0; ks < 2; ++ks) {
            v8bf kb[4];
#pragma unroll
            for (int ktile = 0; ktile < 4; ++ktile)
                kb[ktile] = *reinterpret_cast<const v8bf*>(
                    &Ks[(ktile * 16 + l15) * 64 + ((ks * 4 + quad) ^ l7) * 8]);
#pragma unroll
            for (int ktile = 0; ktile < 4; ++ktile)
                st[ktile] = MFMA16(kb[ktile], qf[ks], st[ktile]);
        }

        const bool diagI = (kt == t);
        float rm = -1e30f;
#pragma unroll
        for (int ktile = 0; ktile < 4; ++ktile) {
            if (diagI && ktile > w) continue;        // fully masked subtile
#pragma unroll
            for (int r = 0; r < 4; ++r) {
                float v = st[ktile][r];
                if (diagI && ktile == w) {
                    int kg = kt * 64 + ktile * 16 + quad * 4 + r;
                    if (kg > qg) v = -1e30f;
                }
                st[ktile][r] = v;
                rm = fmaxf(rm, v);
            }
        }
        rm = fmaxf(rm, __shfl_xor(rm, 16));
        rm = fmaxf(rm, __shfl_xor(rm, 32));
        float mn = fmaxf(mrow, rm);
        float alpha = exp2f(mrow - mn);
        mrow = mn;
        float rs = 0.f;
        const int prow = (w * 16 + l15) * 72;
#pragma unroll
        for (int ktile = 0; ktile < 4; ++ktile) {
            union { bf16_t h[4]; int2 v; } u;
            if (diagI && ktile > w) {
                u.v.x = 0; u.v.y = 0;
            } else {
#pragma unroll
                for (int r = 0; r < 4; ++r) {
                    float p = exp2f(st[ktile][r] - mn);
                    rs += p;
                    u.h[r] = (bf16_t)p;
                }
            }
            *reinterpret_cast<int2*>(&Ps[prow + ktile * 16 + quad * 4]) = u.v;
        }
        rs += __shfl_xor(rs, 16);
        rs += __shfl_xor(rs, 32);
        lrow = lrow * alpha + rs;
#pragma unroll
        for (int dt = 0; dt < 4; ++dt)
#pragma unroll
            for (int r = 0; r < 4; ++r)
                acc_o[dt][r] *= alpha;

        // O^T += V^T P^T  (A=V^T: m=d=l15, k=key; B=P^T: n=q=l15, k=key)
#pragma unroll
        for (int ks = 0; ks < 2; ++ks) {
            v8bf vb[4];
#pragma unroll
            for (int dt = 0; dt < 4; ++dt)
                vb[dt] = *reinterpret_cast<const v8bf*>(
                    &Vs[(dt * 16 + l15) * 64 + ((ks * 4 + quad) ^ l7) * 8]);
            v8bf pf = *reinterpret_cast<const v8bf*>(
                &Ps[(w * 16 + l15) * 72 + ks * 32 + quad * 8]);
#pragma unroll
            for (int dt = 0; dt < 4; ++dt)
                acc_o[dt] = MFMA16(vb[dt], pf, acc_o[dt]);
        }
        __syncthreads();   // all waves done with Ks/Vs before next stage
    }

    // epilogue: lane holds q=l15 (col), d=quad*4+r per dtile -> d-contig int2
    const int bO = bh >> 4, hO = bh & 15;
    float rinv = 1.f / lrow;
    int s = q0 + w * 16 + l15;
#pragma unroll
    for (int dt = 0; dt < 4; ++dt) {
        union { bf16_t h[4]; int2 v; } u;
#pragma unroll
        for (int r = 0; r < 4; ++r)
            u.h[r] = (bf16_t)(acc_o[dt][r] * rinv);
        *reinterpret_cast<int2*>(
            &O[((size_t)bO * SEQ + s) * DM + hO * 64 + dt * 16 + quad * 4]) = u.v;
    }
}

// ---------------------------------------------------------------------------
extern "C" void kernel_launch(void* const* d_in, const int* in_sizes, int n_in,
                              void* d_out, int out_size, void* d_ws, size_t ws_size,
                              hipStream_t stream) {
    const float* x  = (const float*)d_in[0];
    const float* Wq = (const float*)d_in[1];
    const float* bq = (const float*)d_in[2];
    const float* Wk = (const float*)d_in[3];
    const float* bk = (const float*)d_in[4];
    const float* Wv = (const float*)d_in[5];
    const float* bv = (const float*)d_in[6];
    const float* Wo = (const float*)d_in[7];
    const float* bo = (const float*)d_in[8];

    bf16_t* ws = (bf16_t*)d_ws;
    bf16_t* xb     = ws;                   // [4096,1024]        4M  (dead after QKV)
    bf16_t* WqkvT  = ws + 4194304;         // [3,1024n,1024k]    3M
    bf16_t* WoT    = ws + 7340032;         // [1024n,1024k]      1M
    bf16_t* Qb     = ws + 8388608;         // [B,H,S,hd]  pre-scaled 0.125*log2(e)
    bf16_t* Kb     = ws + 12582912;        // [B,H,S,hd]
    bf16_t* Vb     = ws + 16777216;        // [B,H,hd,S]
    bf16_t* Ob     = ws;                   // [B,S,D]  aliases xb (stream-ordered safe)

    conv_x_kernel<<<2048, 256, 0, stream>>>(x, xb);
    conv_wt_kernel<<<dim3(32, 32, 4), 256, 0, stream>>>(Wq, Wk, Wv, Wo, WqkvT, WoT);
    gemm_bt_kernel<1><<<dim3(24, 32), 256, 0, stream>>>(xb, WqkvT, bq, bk, bv, Qb, Kb, Vb);
    attn_kernel<<<dim3(32, 32), 256, 0, stream>>>(Qb, Kb, Vb, Ob);
    gemm_bt_kernel<0><<<dim3(8, 32), 256, 0, stream>>>(Ob, WoT, bo, nullptr, nullptr,
                                                       d_out, nullptr, nullptr);
}